// Round 4
// baseline (65.123 us; speedup 1.0000x reference)
//
#include <hip/hip_runtime.h>
#include <cmath>

#define THREADS 256
#define QC 24000
#define NQ4 (QC / 4)
#define NCLS 80
#define NTOP 300
#define NHIST 4096
#define CAND_CAP 1024

typedef unsigned long long ull;

// monotonic unsigned key for fp32 (total order matching float compare)
__device__ __forceinline__ unsigned fkey(float x) {
    unsigned b = __float_as_uint(x);
    return (b & 0x80000000u) ? ~b : (b | 0x80000000u);
}
__device__ __forceinline__ float fkey_inv(unsigned key) {
    unsigned b = (key & 0x80000000u) ? (key & 0x7fffffffu) : ~key;
    return __uint_as_float(b);
}
// Replicate float32 sigmoid: 1/(1+expf(-x)); double exp rounds to CR expf.
__device__ __forceinline__ float sigmoid_ref(float x) {
    float ef = (float)exp(-(double)x);
    return 1.0f / (1.0f + ef);
}

// bitonic compare-exchange select: element keeps max iff (desc != up)
__device__ __forceinline__ ull csel(bool desc, bool up, ull v, ull p) {
    ull mx = v > p ? v : p;
    ull mn = v > p ? p : v;
    return (desc != up) ? mx : mn;
}

__global__ __launch_bounds__(THREADS, 8) void postproc_kernel(
    const float* __restrict__ logits,   // [B, 300, 80]
    const float* __restrict__ pboxes,   // [B, 300, 4]
    const float* __restrict__ osizes,   // [B, 2]
    float* __restrict__ out_boxes,      // [B, 300, 4]
    float* __restrict__ out_labels,     // [B, 300]
    float* __restrict__ out_scores)     // [B, 300]
{
    const int b = blockIdx.x;
    const int tid = threadIdx.x;
    const int lane = tid & 63;
    const float* __restrict__ row = logits + (size_t)b * QC;
    const float4* __restrict__ row4 = (const float4*)row;

    __shared__ ull cand[CAND_CAP];          // 8 KB (sort scratch / fallback)
    __shared__ unsigned hist[NHIST / 2];    // 8 KB packed u16 (fallback only)
    __shared__ unsigned wsum[THREADS / 64];
    __shared__ int s_ncand;
    __shared__ unsigned s_thresh;

    if (tid == 0) s_ncand = 0;
    __syncthreads();

    // Speculative static threshold (rank-300 logit ~2.24 for N(0,1) data;
    // 2.11 keeps ~420 +- 20 candidates). Validity checked; exact histogram
    // fallback below if any row violates it.
    const float T0 = 2.11f;

    auto push = [&](float x, unsigned idx) {
        bool pred = x >= T0;
        ull mask = __ballot(pred);
        if (mask) {
            int leader = __ffsll((long long)mask) - 1;
            int base = 0;
            if (lane == leader) base = atomicAdd(&s_ncand, __popcll(mask));
            base = __shfl(base, leader, 64);
            if (pred) {
                int pos = base + __popcll(mask & ((1ull << lane) - 1));
                if (pos < CAND_CAP)
                    cand[pos] = ((ull)fkey(x) << 32) | (ull)(~idx);
            }
        }
    };

    // ---- single pass over logits, 4x unrolled for ILP ----
    int i = tid;
    for (; i < NQ4 - 768; i += 1024) {
        float4 a = row4[i];
        float4 c = row4[i + 256];
        float4 d = row4[i + 512];
        float4 e = row4[i + 768];
        push(a.x, 4 * i + 0);         push(a.y, 4 * i + 1);
        push(a.z, 4 * i + 2);         push(a.w, 4 * i + 3);
        push(c.x, 4 * (i + 256));     push(c.y, 4 * (i + 256) + 1);
        push(c.z, 4 * (i + 256) + 2); push(c.w, 4 * (i + 256) + 3);
        push(d.x, 4 * (i + 512));     push(d.y, 4 * (i + 512) + 1);
        push(d.z, 4 * (i + 512) + 2); push(d.w, 4 * (i + 512) + 3);
        push(e.x, 4 * (i + 768));     push(e.y, 4 * (i + 768) + 1);
        push(e.z, 4 * (i + 768) + 2); push(e.w, 4 * (i + 768) + 3);
    }
    for (; i < NQ4; i += 256) {
        float4 a = row4[i];
        push(a.x, 4 * i + 0);
        push(a.y, 4 * i + 1);
        push(a.z, 4 * i + 2);
        push(a.w, 4 * i + 3);
    }
    __syncthreads();
    int nc = s_ncand;

    ull va, vb;   // register-resident elements tid and tid+256

    if (nc >= NTOP && nc <= 512) {
        // ==== fast path: register bitonic sort of 512 ====
        va = (tid < nc) ? cand[tid] : 0ull;
        vb = (tid + 256 < nc) ? cand[tid + 256] : 0ull;

        // dense sigmoid on registers (key -> score bits), padding stays 0
        if (va) {
            float sc = sigmoid_ref(fkey_inv((unsigned)(va >> 32)));
            va = ((ull)__float_as_uint(sc) << 32) | (va & 0xffffffffull);
        }
        if (vb) {
            float sc = sigmoid_ref(fkey_inv((unsigned)(vb >> 32)));
            vb = ((ull)__float_as_uint(sc) << 32) | (vb & 0xffffffffull);
        }
        __syncthreads();   // cand[] reads done before reuse as exchange buffer

        for (int k = 2; k <= 512; k <<= 1) {
            for (int j = k >> 1; j > 0; j >>= 1) {
                bool desc_a = (tid & k) == 0;
                bool desc_b = ((tid + 256) & k) == 0;
                bool up = (tid & j) != 0;
                if (j == 256) {
                    ull mx = va > vb ? va : vb;
                    ull mn = va > vb ? vb : va;
                    va = mx; vb = mn;           // both in descending block
                } else if (j >= 64) {
                    cand[tid] = va;
                    cand[tid + 256] = vb;
                    __syncthreads();
                    ull pa = cand[tid ^ j];
                    ull pb = cand[(tid ^ j) + 256];
                    __syncthreads();
                    va = csel(desc_a, up, va, pa);
                    vb = csel(desc_b, up, vb, pb);
                } else {
                    ull pa = (ull)__shfl_xor((long long)va, j, 64);
                    ull pb = (ull)__shfl_xor((long long)vb, j, 64);
                    va = csel(desc_a, up, va, pa);
                    vb = csel(desc_b, up, vb, pb);
                }
            }
        }
    } else {
        // ==== fallback: exact histogram threshold + LDS bitonic (<=1024) ====
        for (int j = tid; j < NHIST / 2; j += THREADS) hist[j] = 0u;
        __syncthreads();
        for (int j = tid; j < NQ4; j += THREADS) {
            float4 v = row4[j];
            float vals[4] = {v.x, v.y, v.z, v.w};
            #pragma unroll
            for (int s = 0; s < 4; ++s) {
                unsigned bin = fkey(vals[s]) >> 20;
                atomicAdd(&hist[bin >> 1], (bin & 1) ? 0x10000u : 1u);
            }
        }
        __syncthreads();
        const int CHUNK = NHIST / THREADS;          // 16
        const int base = NHIST - 1 - tid * CHUNK;
        unsigned partial = 0;
        #pragma unroll
        for (int s = 0; s < CHUNK; ++s) {
            int bin = base - s;
            partial += (hist[bin >> 1] >> ((bin & 1) * 16)) & 0xffffu;
        }
        unsigned run = partial;
        #pragma unroll
        for (int d = 1; d < 64; d <<= 1) {
            unsigned v = __shfl_up(run, d, 64);
            if (lane >= d) run += v;
        }
        if (lane == 63) wsum[tid >> 6] = run;
        __syncthreads();
        unsigned off = 0;
        for (int w = 0; w < (tid >> 6); ++w) off += wsum[w];
        unsigned incl = run + off, excl = incl - partial;
        if (excl < NTOP && incl >= NTOP) {
            unsigned cum = excl;
            #pragma unroll
            for (int s = 0; s < CHUNK; ++s) {
                int bin = base - s;
                cum += (hist[bin >> 1] >> ((bin & 1) * 16)) & 0xffffu;
                if (cum >= NTOP) { s_thresh = (unsigned)bin << 20; break; }
            }
        }
        if (tid == 0) s_ncand = 0;
        __syncthreads();
        const unsigned T = s_thresh;
        for (int j = tid; j < NQ4; j += THREADS) {
            float4 v = row4[j];
            float vals[4] = {v.x, v.y, v.z, v.w};
            #pragma unroll
            for (int s = 0; s < 4; ++s) {
                unsigned k = fkey(vals[s]);
                if (k >= T) {
                    int pos = atomicAdd(&s_ncand, 1);
                    if (pos < CAND_CAP)
                        cand[pos] = ((ull)k << 32) | (ull)(~(unsigned)(4 * j + s));
                }
            }
        }
        __syncthreads();
        nc = min(s_ncand, CAND_CAP);

        for (int j = tid; j < nc; j += THREADS) {
            ull c = cand[j];
            float sc = sigmoid_ref(fkey_inv((unsigned)(c >> 32)));
            cand[j] = ((ull)__float_as_uint(sc) << 32) | (c & 0xffffffffull);
        }
        int npad = 512;
        while (npad < nc) npad <<= 1;
        for (int j = nc + tid; j < npad; j += THREADS) cand[j] = 0ull;
        __syncthreads();
        for (int k = 2; k <= npad; k <<= 1) {
            for (int j = k >> 1; j > 0; j >>= 1) {
                for (int t = tid; t < (npad >> 1); t += THREADS) {
                    int u = ((t & ~(j - 1)) << 1) | (t & (j - 1));
                    int uxj = u | j;
                    ull a = cand[u], c = cand[uxj];
                    bool desc = (u & k) == 0;
                    bool sw = desc ? (a < c) : (a > c);
                    if (sw) { cand[u] = c; cand[uxj] = a; }
                }
                __syncthreads();
            }
        }
        va = cand[tid];
        vb = cand[tid + 256];
    }

    // ---- emit top-300 from registers ----
    const float o0 = osizes[2 * b], o1 = osizes[2 * b + 1];
    const float4* __restrict__ pb4 = (const float4*)pboxes + (size_t)b * NTOP;
    float4* __restrict__ ob4 = (float4*)out_boxes + (size_t)b * NTOP;

    auto emit = [&](int r, ull c) {
        float sc = __uint_as_float((unsigned)(c >> 32));
        unsigned idx = ~((unsigned)c);
        unsigned q = idx / NCLS;
        unsigned cls = idx - q * NCLS;
        out_scores[(size_t)b * NTOP + r] = sc;
        out_labels[(size_t)b * NTOP + r] = (float)cls;
        float4 pb = pb4[q];
        float4 ob;
        ob.x = (pb.x - 0.5f * pb.z) * o0;
        ob.y = (pb.y - 0.5f * pb.w) * o1;
        ob.z = (pb.x + 0.5f * pb.z) * o0;
        ob.w = (pb.y + 0.5f * pb.w) * o1;
        ob4[r] = ob;
    };
    emit(tid, va);
    if (tid < NTOP - 256) emit(tid + 256, vb);
}

extern "C" void kernel_launch(void* const* d_in, const int* in_sizes, int n_in,
                              void* d_out, int out_size, void* d_ws, size_t ws_size,
                              hipStream_t stream) {
    const float* logits = (const float*)d_in[0];
    const float* pboxes = (const float*)d_in[1];
    const float* osizes = (const float*)d_in[2];
    const int B = in_sizes[2] / 2;

    float* out_boxes  = (float*)d_out;                       // B*300*4
    float* out_labels = out_boxes + (size_t)B * NTOP * 4;    // B*300
    float* out_scores = out_labels + (size_t)B * NTOP;       // B*300

    hipLaunchKernelGGL(postproc_kernel, dim3(B), dim3(THREADS), 0, stream,
                       logits, pboxes, osizes, out_boxes, out_labels, out_scores);
}

// Round 5
// 64.086 us; speedup vs baseline: 1.0162x; 1.0162x over previous
//
#include <hip/hip_runtime.h>
#include <cmath>

#define THREADS 256
#define QC 24000
#define NQ4 (QC / 4)
#define HALF4 (NQ4 / 2)
#define NCLS 80
#define NTOP 300
#define NHIST 4096
#define CAP_ROW 1024

typedef unsigned long long ull;

// monotonic unsigned key for fp32 (total order matching float compare)
__device__ __forceinline__ unsigned fkey(float x) {
    unsigned b = __float_as_uint(x);
    return (b & 0x80000000u) ? ~b : (b | 0x80000000u);
}
__device__ __forceinline__ float fkey_inv(unsigned key) {
    unsigned b = (key & 0x80000000u) ? (key & 0x7fffffffu) : ~key;
    return __uint_as_float(b);
}
// Replicate float32 sigmoid: 1/(1+expf(-x)); double exp rounds to CR expf.
__device__ __forceinline__ float sigmoid_ref(float x) {
    float ef = (float)exp(-(double)x);
    return 1.0f / (1.0f + ef);
}

// Speculative static threshold: rank-300 logit ~2.24 for N(0,1)*24000;
// 2.11 keeps ~420 +- 20 candidates/row. Checked per row; exact histogram
// fallback in sort_emit_kernel if violated.
#define T0 2.11f

__global__ void init_kernel(unsigned* __restrict__ gcnt, int B) {
    int i = blockIdx.x * blockDim.x + threadIdx.x;
    if (i < B) gcnt[i] = 0u;
}

// ---- kernel A: BW-bound scan; 2 blocks per row ----
__global__ __launch_bounds__(THREADS, 8) void scan_kernel(
    const float* __restrict__ logits,
    ull* __restrict__ gcand,            // [B, CAP_ROW]
    unsigned* __restrict__ gcnt)        // [B]
{
    const int blk = blockIdx.x;
    const int row = blk >> 1;
    const int half = blk & 1;
    const int tid = threadIdx.x;
    const float4* __restrict__ row4 =
        (const float4*)(logits + (size_t)row * QC) + half * HALF4;
    const int ibase = half * (HALF4 * 4);

    __shared__ ull lcand[CAP_ROW];      // 8 KB
    __shared__ int lcnt;
    __shared__ int s_base;

    if (tid == 0) lcnt = 0;
    __syncthreads();

    auto handle = [&](float4 v, int j) {
        int e = ibase + 4 * j;
        if (v.x >= T0) { int p = atomicAdd(&lcnt, 1); if (p < CAP_ROW)
            lcand[p] = ((ull)fkey(v.x) << 32) | (ull)(~(unsigned)(e + 0)); }
        if (v.y >= T0) { int p = atomicAdd(&lcnt, 1); if (p < CAP_ROW)
            lcand[p] = ((ull)fkey(v.y) << 32) | (ull)(~(unsigned)(e + 1)); }
        if (v.z >= T0) { int p = atomicAdd(&lcnt, 1); if (p < CAP_ROW)
            lcand[p] = ((ull)fkey(v.z) << 32) | (ull)(~(unsigned)(e + 2)); }
        if (v.w >= T0) { int p = atomicAdd(&lcnt, 1); if (p < CAP_ROW)
            lcand[p] = ((ull)fkey(v.w) << 32) | (ull)(~(unsigned)(e + 3)); }
    };

    int j = tid;
    for (; j + THREADS < HALF4; j += 2 * THREADS) {
        float4 a = row4[j];
        float4 b2 = row4[j + THREADS];
        handle(a, j);
        handle(b2, j + THREADS);
    }
    for (; j < HALF4; j += THREADS) handle(row4[j], j);

    __syncthreads();
    int n = lcnt;                         // unclamped (overflow detection)
    if (tid == 0) s_base = (int)atomicAdd(&gcnt[row], (unsigned)n);
    __syncthreads();
    int base = s_base;
    int nw = min(n, CAP_ROW);
    for (int i = tid; i < nw; i += THREADS) {
        int p = base + i;
        if (p < CAP_ROW) gcand[(size_t)row * CAP_ROW + p] = lcand[i];
    }
}

// ---- kernel B: sigmoid + sort + emit; 1 block per row ----
__global__ __launch_bounds__(THREADS, 8) void sort_emit_kernel(
    const float* __restrict__ logits,
    const float* __restrict__ pboxes,
    const float* __restrict__ osizes,
    const ull* __restrict__ gcand,
    const unsigned* __restrict__ gcnt,
    float* __restrict__ out_boxes,
    float* __restrict__ out_labels,
    float* __restrict__ out_scores,
    int use_ws)
{
    const int b = blockIdx.x;
    const int tid = threadIdx.x;
    const int lane = tid & 63;
    const float* __restrict__ row = logits + (size_t)b * QC;
    const float4* __restrict__ row4 = (const float4*)row;

    __shared__ ull cand[CAP_ROW];           // 8 KB
    __shared__ unsigned hist[NHIST / 2];    // 8 KB packed u16 (fallback only)
    __shared__ unsigned wsum[THREADS / 64];
    __shared__ int s_ncand;
    __shared__ unsigned s_thresh;

    int nc = use_ws ? (int)gcnt[b] : -1;

    if (nc >= NTOP && nc <= CAP_ROW) {
        // fast path: load candidates (L2-hot), dense sigmoid
        const ull* __restrict__ g = gcand + (size_t)b * CAP_ROW;
        for (int i = tid; i < nc; i += THREADS) {
            ull c = g[i];
            float sc = sigmoid_ref(fkey_inv((unsigned)(c >> 32)));
            cand[i] = ((ull)__float_as_uint(sc) << 32) | (c & 0xffffffffull);
        }
    } else {
        // ---- exact fallback: histogram threshold + collect ----
        for (int i = tid; i < NHIST / 2; i += THREADS) hist[i] = 0u;
        if (tid == 0) s_ncand = 0;
        __syncthreads();
        for (int i = tid; i < NQ4; i += THREADS) {
            float4 v = row4[i];
            float vals[4] = {v.x, v.y, v.z, v.w};
            #pragma unroll
            for (int s = 0; s < 4; ++s) {
                unsigned bin = fkey(vals[s]) >> 20;
                atomicAdd(&hist[bin >> 1], (bin & 1) ? 0x10000u : 1u);
            }
        }
        __syncthreads();
        const int CHUNK = NHIST / THREADS;          // 16
        const int base = NHIST - 1 - tid * CHUNK;
        unsigned partial = 0;
        #pragma unroll
        for (int s = 0; s < CHUNK; ++s) {
            int bin = base - s;
            partial += (hist[bin >> 1] >> ((bin & 1) * 16)) & 0xffffu;
        }
        unsigned run = partial;
        #pragma unroll
        for (int d = 1; d < 64; d <<= 1) {
            unsigned v = __shfl_up(run, d, 64);
            if (lane >= d) run += v;
        }
        if (lane == 63) wsum[tid >> 6] = run;
        __syncthreads();
        unsigned off = 0;
        for (int w = 0; w < (tid >> 6); ++w) off += wsum[w];
        unsigned incl = run + off, excl = incl - partial;
        if (excl < NTOP && incl >= NTOP) {
            unsigned cum = excl;
            #pragma unroll
            for (int s = 0; s < CHUNK; ++s) {
                int bin = base - s;
                cum += (hist[bin >> 1] >> ((bin & 1) * 16)) & 0xffffu;
                if (cum >= NTOP) { s_thresh = (unsigned)bin << 20; break; }
            }
        }
        __syncthreads();
        const unsigned T = s_thresh;
        for (int i = tid; i < NQ4; i += THREADS) {
            float4 v = row4[i];
            float vals[4] = {v.x, v.y, v.z, v.w};
            #pragma unroll
            for (int s = 0; s < 4; ++s) {
                unsigned k = fkey(vals[s]);
                if (k >= T) {
                    int pos = atomicAdd(&s_ncand, 1);
                    if (pos < CAP_ROW)
                        cand[pos] = ((ull)k << 32) | (ull)(~(unsigned)(4 * i + s));
                }
            }
        }
        __syncthreads();
        nc = min(s_ncand, CAP_ROW);
        for (int i = tid; i < nc; i += THREADS) {
            ull c = cand[i];
            float sc = sigmoid_ref(fkey_inv((unsigned)(c >> 32)));
            cand[i] = ((ull)__float_as_uint(sc) << 32) | (c & 0xffffffffull);
        }
    }

    int npad = 512;
    while (npad < nc) npad <<= 1;
    for (int i = nc + tid; i < npad; i += THREADS) cand[i] = 0ull;
    __syncthreads();

    // ---- bitonic sort, descending on composite (score, ~idx) ----
    for (int k = 2; k <= npad; k <<= 1) {
        for (int j = k >> 1; j > 0; j >>= 1) {
            for (int t = tid; t < (npad >> 1); t += THREADS) {
                int u = ((t & ~(j - 1)) << 1) | (t & (j - 1));
                int uxj = u | j;
                ull a = cand[u], c = cand[uxj];
                bool desc = (u & k) == 0;
                bool sw = desc ? (a < c) : (a > c);
                if (sw) { cand[u] = c; cand[uxj] = a; }
            }
            __syncthreads();
        }
    }

    // ---- emit top-300 ----
    const float o0 = osizes[2 * b], o1 = osizes[2 * b + 1];
    const float4* __restrict__ pb4 = (const float4*)pboxes + (size_t)b * NTOP;
    float4* __restrict__ ob4 = (float4*)out_boxes + (size_t)b * NTOP;
    for (int r = tid; r < NTOP; r += THREADS) {
        ull c = cand[r];
        float sc = __uint_as_float((unsigned)(c >> 32));
        unsigned idx = ~((unsigned)c);
        unsigned q = idx / NCLS;
        unsigned cls = idx - q * NCLS;
        out_scores[(size_t)b * NTOP + r] = sc;
        out_labels[(size_t)b * NTOP + r] = (float)cls;
        float4 pb = pb4[q];
        float4 ob;
        ob.x = (pb.x - 0.5f * pb.z) * o0;
        ob.y = (pb.y - 0.5f * pb.w) * o1;
        ob.z = (pb.x + 0.5f * pb.z) * o0;
        ob.w = (pb.y + 0.5f * pb.w) * o1;
        ob4[r] = ob;
    }
}

extern "C" void kernel_launch(void* const* d_in, const int* in_sizes, int n_in,
                              void* d_out, int out_size, void* d_ws, size_t ws_size,
                              hipStream_t stream) {
    const float* logits = (const float*)d_in[0];
    const float* pboxes = (const float*)d_in[1];
    const float* osizes = (const float*)d_in[2];
    const int B = in_sizes[2] / 2;

    float* out_boxes  = (float*)d_out;                       // B*300*4
    float* out_labels = out_boxes + (size_t)B * NTOP * 4;    // B*300
    float* out_scores = out_labels + (size_t)B * NTOP;       // B*300

    // workspace layout: [counters: B u32 (aligned to 4KB)] [cand: B*CAP_ROW u64]
    size_t cnt_bytes = ((size_t)B * 4 + 4095) & ~(size_t)4095;
    size_t need = cnt_bytes + (size_t)B * CAP_ROW * 8;
    int use_ws = (ws_size >= need) ? 1 : 0;

    unsigned* gcnt = (unsigned*)d_ws;
    ull* gcand = (ull*)((char*)d_ws + cnt_bytes);

    if (use_ws) {
        hipLaunchKernelGGL(init_kernel, dim3((B + 255) / 256), dim3(256), 0, stream,
                           gcnt, B);
        hipLaunchKernelGGL(scan_kernel, dim3(2 * B), dim3(THREADS), 0, stream,
                           logits, gcand, gcnt);
    }
    hipLaunchKernelGGL(sort_emit_kernel, dim3(B), dim3(THREADS), 0, stream,
                       logits, pboxes, osizes, gcand, gcnt,
                       out_boxes, out_labels, out_scores, use_ws);
}

// Round 6
// 59.170 us; speedup vs baseline: 1.1006x; 1.0831x over previous
//
#include <hip/hip_runtime.h>
#include <cmath>

#define THREADS 256
#define QC 24000
#define NQ4 (QC / 4)
#define NCLS 80
#define NTOP 300
#define NHIST 4096
#define CAP_ROW 1024

typedef unsigned long long ull;
typedef float f32x4 __attribute__((ext_vector_type(4)));

// monotonic unsigned key for fp32 (total order matching float compare)
__device__ __forceinline__ unsigned fkey(float x) {
    unsigned b = __float_as_uint(x);
    return (b & 0x80000000u) ? ~b : (b | 0x80000000u);
}
__device__ __forceinline__ float fkey_inv(unsigned key) {
    unsigned b = (key & 0x80000000u) ? (key & 0x7fffffffu) : ~key;
    return __uint_as_float(b);
}
// Replicate float32 sigmoid: 1/(1+expf(-x)); double exp rounds to CR expf.
__device__ __forceinline__ float sigmoid_ref(float x) {
    float ef = (float)exp(-(double)x);
    return 1.0f / (1.0f + ef);
}

// Speculative static threshold: rank-300 logit ~2.24 for this data; 2.11
// keeps ~420 +- 20 candidates/row. Checked on-device; exact histogram
// fallback below if any row violates [NTOP, CAP_ROW].
#define T0 2.11f

__global__ __launch_bounds__(THREADS, 8) void postproc_kernel(
    const float* __restrict__ logits,   // [B, 300, 80]
    const float* __restrict__ pboxes,   // [B, 300, 4]
    const float* __restrict__ osizes,   // [B, 2]
    float* __restrict__ out_boxes,      // [B, 300, 4]
    float* __restrict__ out_labels,     // [B, 300]
    float* __restrict__ out_scores)     // [B, 300]
{
    const int b = blockIdx.x;
    const int tid = threadIdx.x;
    const int lane = tid & 63;
    const f32x4* __restrict__ row4 = (const f32x4*)(logits + (size_t)b * QC);

    __shared__ ull cand[CAP_ROW];           // 8 KB
    __shared__ unsigned hist[NHIST / 2];    // 8 KB packed u16 (fallback only)
    __shared__ unsigned wsum[THREADS / 64];
    __shared__ int s_ncand;
    __shared__ unsigned s_thresh;

    if (tid == 0) s_ncand = 0;
    __syncthreads();

    // per-lane predicated push; branch taken by ~1.9% of lanes
    auto pushe = [&](float x, int idx) {
        if (x >= T0) {
            int p = atomicAdd(&s_ncand, 1);
            if (p < CAP_ROW)
                cand[p] = ((ull)fkey(x) << 32) | (ull)(~(unsigned)idx);
        }
    };
    auto handle = [&](f32x4 v, int i) {
        pushe(v.x, 4 * i);
        pushe(v.y, 4 * i + 1);
        pushe(v.z, 4 * i + 2);
        pushe(v.w, 4 * i + 3);
    };

    // ---- single streaming pass, 4 loads in flight, nontemporal ----
    int i = tid;
    for (; i + 768 < NQ4; i += 1024) {
        f32x4 a = __builtin_nontemporal_load(row4 + i);
        f32x4 c = __builtin_nontemporal_load(row4 + i + 256);
        f32x4 d = __builtin_nontemporal_load(row4 + i + 512);
        f32x4 e = __builtin_nontemporal_load(row4 + i + 768);
        handle(a, i);
        handle(c, i + 256);
        handle(d, i + 512);
        handle(e, i + 768);
    }
    for (; i < NQ4; i += 256)
        handle(__builtin_nontemporal_load(row4 + i), i);
    __syncthreads();
    int nc = s_ncand;

    if (nc >= NTOP && nc <= CAP_ROW) {
        // ---- fast path: dense sigmoid in place (key -> score bits) ----
        for (int j = tid; j < nc; j += THREADS) {
            ull c = cand[j];
            float sc = sigmoid_ref(fkey_inv((unsigned)(c >> 32)));
            cand[j] = ((ull)__float_as_uint(sc) << 32) | (c & 0xffffffffull);
        }
    } else {
        // ---- exact fallback: histogram threshold + re-collect ----
        for (int j = tid; j < NHIST / 2; j += THREADS) hist[j] = 0u;
        __syncthreads();
        for (int j = tid; j < NQ4; j += THREADS) {
            f32x4 v = row4[j];
            float vals[4] = {v.x, v.y, v.z, v.w};
            #pragma unroll
            for (int s = 0; s < 4; ++s) {
                unsigned bin = fkey(vals[s]) >> 20;
                atomicAdd(&hist[bin >> 1], (bin & 1) ? 0x10000u : 1u);
            }
        }
        __syncthreads();
        const int CHUNK = NHIST / THREADS;          // 16
        const int base = NHIST - 1 - tid * CHUNK;
        unsigned partial = 0;
        #pragma unroll
        for (int s = 0; s < CHUNK; ++s) {
            int bin = base - s;
            partial += (hist[bin >> 1] >> ((bin & 1) * 16)) & 0xffffu;
        }
        unsigned run = partial;
        #pragma unroll
        for (int d = 1; d < 64; d <<= 1) {
            unsigned v = __shfl_up(run, d, 64);
            if (lane >= d) run += v;
        }
        if (lane == 63) wsum[tid >> 6] = run;
        __syncthreads();
        unsigned off = 0;
        for (int w = 0; w < (tid >> 6); ++w) off += wsum[w];
        unsigned incl = run + off, excl = incl - partial;
        if (excl < NTOP && incl >= NTOP) {
            unsigned cum = excl;
            #pragma unroll
            for (int s = 0; s < CHUNK; ++s) {
                int bin = base - s;
                cum += (hist[bin >> 1] >> ((bin & 1) * 16)) & 0xffffu;
                if (cum >= NTOP) { s_thresh = (unsigned)bin << 20; break; }
            }
        }
        if (tid == 0) s_ncand = 0;
        __syncthreads();
        const unsigned T = s_thresh;
        for (int j = tid; j < NQ4; j += THREADS) {
            f32x4 v = row4[j];
            float vals[4] = {v.x, v.y, v.z, v.w};
            #pragma unroll
            for (int s = 0; s < 4; ++s) {
                unsigned k = fkey(vals[s]);
                if (k >= T) {
                    int pos = atomicAdd(&s_ncand, 1);
                    if (pos < CAP_ROW)
                        cand[pos] = ((ull)k << 32) | (ull)(~(unsigned)(4 * j + s));
                }
            }
        }
        __syncthreads();
        nc = min(s_ncand, CAP_ROW);
        for (int j = tid; j < nc; j += THREADS) {
            ull c = cand[j];
            float sc = sigmoid_ref(fkey_inv((unsigned)(c >> 32)));
            cand[j] = ((ull)__float_as_uint(sc) << 32) | (c & 0xffffffffull);
        }
    }

    int npad = 512;
    while (npad < nc) npad <<= 1;
    for (int j = nc + tid; j < npad; j += THREADS) cand[j] = 0ull;
    __syncthreads();

    // ---- bitonic sort, descending on composite (score, ~idx) ----
    for (int k = 2; k <= npad; k <<= 1) {
        for (int j = k >> 1; j > 0; j >>= 1) {
            for (int t = tid; t < (npad >> 1); t += THREADS) {
                int u = ((t & ~(j - 1)) << 1) | (t & (j - 1));
                int uxj = u | j;
                ull a = cand[u], c = cand[uxj];
                bool desc = (u & k) == 0;
                bool sw = desc ? (a < c) : (a > c);
                if (sw) { cand[u] = c; cand[uxj] = a; }
            }
            __syncthreads();
        }
    }

    // ---- emit top-300 ----
    const float o0 = osizes[2 * b], o1 = osizes[2 * b + 1];
    const float4* __restrict__ pb4 = (const float4*)pboxes + (size_t)b * NTOP;
    float4* __restrict__ ob4 = (float4*)out_boxes + (size_t)b * NTOP;
    for (int r = tid; r < NTOP; r += THREADS) {
        ull c = cand[r];
        float sc = __uint_as_float((unsigned)(c >> 32));
        unsigned idx = ~((unsigned)c);
        unsigned q = idx / NCLS;
        unsigned cls = idx - q * NCLS;
        out_scores[(size_t)b * NTOP + r] = sc;
        out_labels[(size_t)b * NTOP + r] = (float)cls;
        float4 pb = pb4[q];
        float4 ob;
        ob.x = (pb.x - 0.5f * pb.z) * o0;
        ob.y = (pb.y - 0.5f * pb.w) * o1;
        ob.z = (pb.x + 0.5f * pb.z) * o0;
        ob.w = (pb.y + 0.5f * pb.w) * o1;
        ob4[r] = ob;
    }
}

extern "C" void kernel_launch(void* const* d_in, const int* in_sizes, int n_in,
                              void* d_out, int out_size, void* d_ws, size_t ws_size,
                              hipStream_t stream) {
    const float* logits = (const float*)d_in[0];
    const float* pboxes = (const float*)d_in[1];
    const float* osizes = (const float*)d_in[2];
    const int B = in_sizes[2] / 2;

    float* out_boxes  = (float*)d_out;                       // B*300*4
    float* out_labels = out_boxes + (size_t)B * NTOP * 4;    // B*300
    float* out_scores = out_labels + (size_t)B * NTOP;       // B*300

    hipLaunchKernelGGL(postproc_kernel, dim3(B), dim3(THREADS), 0, stream,
                       logits, pboxes, osizes, out_boxes, out_labels, out_scores);
}